// Round 3
// baseline (5864.363 us; speedup 1.0000x reference)
//
#include <hip/hip_runtime.h>
#include <hip/hip_bf16.h>

// GIN: N=100000, E=1.6M, G=64, D=128, L=4.
// R3: drop CSR entirely. Single-pass bucketed edge partition (128-node buckets,
// packed (ldst<<17)|src in 4B) + per-bucket LDS fp32 scatter-accumulate
// aggregation (swizzled accumulator -> conflict-free ds_add_f32).
// bf16 feature storage, bf16 MFMA GEMMs with fused BN stats, fused bnpool.

#define N_NODES   100000
#define N_EDGES   1600000
#define N_GRAPHS  64
#define DIM       128
#define N_LAYERS  4
#define CLS_IN    640
#define CLS_HID   256
#define N_CLASSES 10
#define LRELU_SLOPE 0.01f
#define BN_EPS_F    1e-5f

#define NBUCK    782      // ceil(100000/128)
#define BUCK_CAP 4096     // avg fill 2046, max ~2300 -> safe

typedef __attribute__((ext_vector_type(8))) short bf16x8;
typedef __attribute__((ext_vector_type(4))) float f32x4;

__device__ __forceinline__ float lrelu(float x) { return x > 0.f ? x : LRELU_SLOPE * x; }

__device__ __forceinline__ uint pack2(float x, float y) {
    uint a = __float_as_uint(x), b = __float_as_uint(y);
    a = (a + 0x7FFFu + ((a >> 16) & 1u)) >> 16;
    b = (b + 0x7FFFu + ((b >> 16) & 1u)) >> 16;
    return a | (b << 16);
}
__device__ __forceinline__ float2 unpack2(uint v) {
    return make_float2(__uint_as_float(v << 16), __uint_as_float(v & 0xFFFF0000u));
}

// ---------------- weight convert: W[k][n] fp32 -> Wt[n][k] bf16 ----------------
__global__ void k_convert_w(const float* __restrict__ W1, const float* __restrict__ W2,
                            ushort* __restrict__ W1t, ushort* __restrict__ W2t) {
    int gid = blockIdx.x * blockDim.x + threadIdx.x;   // 8 * 16384
    if (gid >= 8 * DIM * DIM) return;
    int mat = gid >> 14, idx = gid & 16383;
    int k = idx >> 7, n = idx & 127;
    const float* src = (mat < 4) ? (W1 + mat * DIM * DIM) : (W2 + (mat - 4) * DIM * DIM);
    ushort* dst = (mat < 4) ? (W1t + mat * DIM * DIM) : (W2t + (mat - 4) * DIM * DIM);
    uint a = __float_as_uint(src[k * DIM + n]);
    dst[n * DIM + k] = (ushort)((a + 0x7FFFu + ((a >> 16) & 1u)) >> 16);
}

// ---------------- initial one-hot features (bf16) ----------------
__global__ void k_build_x(const int* __restrict__ deg, uint* __restrict__ x) {
    int gid = blockIdx.x * blockDim.x + threadIdx.x;   // one per uint (2 bf16)
    if (gid >= N_NODES * 64) return;
    int i = gid >> 6, c = gid & 63;
    int d = deg[i];
    uint v = 0;
    if ((d >> 1) == c) v = 0x3F80u << (16 * (d & 1));
    x[gid] = v;
}

// zs[0] pooling = per-graph degree histogram
__global__ void k_deg_pool(const int* __restrict__ deg, const int* __restrict__ batch,
                           float* __restrict__ pooled) {
    int i = blockIdx.x * blockDim.x + threadIdx.x;
    if (i < N_NODES) atomicAdd(&pooled[batch[i] * CLS_IN + deg[i]], 1.0f);
}

// ---------------- single-pass bucketed edge partition ----------------
// bucket b = dst >> 7 covers nodes [128b, 128b+128); packed = (dst&127)<<17 | src
__global__ void __launch_bounds__(1024) k_partition(const int* __restrict__ src,
                                                    const int* __restrict__ dst,
                                                    uint* __restrict__ cursor,
                                                    uint* __restrict__ ebuf) {
    __shared__ uint hist[NBUCK];
    __shared__ uint basev[NBUCK];
    int t = threadIdx.x;
    for (int b = t; b < NBUCK; b += 1024) hist[b] = 0;
    __syncthreads();
    int e0 = blockIdx.x * 16384;
    uint msrc[16], mdst[16], mrank[16];
#pragma unroll
    for (int i = 0; i < 16; ++i) {
        int e = e0 + i * 1024 + t;
        if (e < N_EDGES) {
            msrc[i] = (uint)src[e];
            mdst[i] = (uint)dst[e];
            mrank[i] = atomicAdd(&hist[mdst[i] >> 7], 1u);
        } else mdst[i] = 0xFFFFFFFFu;
    }
    __syncthreads();
    for (int b = t; b < NBUCK; b += 1024) {
        uint c = hist[b];
        basev[b] = c ? (uint)(b * BUCK_CAP) + atomicAdd(&cursor[b], c) : 0u;
    }
    __syncthreads();
#pragma unroll
    for (int i = 0; i < 16; ++i) {
        if (mdst[i] != 0xFFFFFFFFu) {
            uint b = mdst[i] >> 7;
            ebuf[basev[b] + mrank[i]] = ((mdst[i] & 127u) << 17) | msrc[i];
        }
    }
}

// ---------------- aggregation: per-bucket LDS scatter-accumulate ----------------
// out[n] = (1+eps)*h[n] + sum_{e: dst=n} h[src_e].  Accumulator swizzle:
// feature 2*lane -> col lane, feature 2*lane+1 -> col 64+lane (bank-conflict-free).
__global__ void __launch_bounds__(512) k_agg(const uint* __restrict__ h,
                                             const uint* __restrict__ ebuf,
                                             const uint* __restrict__ cursor,
                                             uint* __restrict__ out,
                                             const float* __restrict__ epsv, int layer) {
    __shared__ float acc[128 * 128];   // 64 KB
    const int t = threadIdx.x, lane = t & 63, wave = t >> 6;
    {
        float4 z = make_float4(0.f, 0.f, 0.f, 0.f);
        for (int i = t; i < 4096; i += 512) ((float4*)acc)[i] = z;
    }
    __syncthreads();
    const int b = blockIdx.x;
    const int cnt = (int)cursor[b];
    const uint* ep = ebuf + b * BUCK_CAP;
    for (int chunk = wave * 64; chunk < cnt; chunk += 512) {
        int n = cnt - chunk; if (n > 64) n = 64;
        uint myv = (lane < n) ? ep[chunk + lane] : 0u;
        int j = 0;
        for (; j + 4 <= n; j += 4) {
            uint u0 = __shfl(myv, j),     u1 = __shfl(myv, j + 1);
            uint u2 = __shfl(myv, j + 2), u3 = __shfl(myv, j + 3);
            uint h0 = h[(u0 & 0x1FFFFu) * 64 + lane];
            uint h1 = h[(u1 & 0x1FFFFu) * 64 + lane];
            uint h2 = h[(u2 & 0x1FFFFu) * 64 + lane];
            uint h3 = h[(u3 & 0x1FFFFu) * 64 + lane];
            float2 f0 = unpack2(h0), f1 = unpack2(h1), f2 = unpack2(h2), f3 = unpack2(h3);
            atomicAdd(&acc[(u0 >> 17) * 128 + lane],      f0.x);
            atomicAdd(&acc[(u0 >> 17) * 128 + 64 + lane], f0.y);
            atomicAdd(&acc[(u1 >> 17) * 128 + lane],      f1.x);
            atomicAdd(&acc[(u1 >> 17) * 128 + 64 + lane], f1.y);
            atomicAdd(&acc[(u2 >> 17) * 128 + lane],      f2.x);
            atomicAdd(&acc[(u2 >> 17) * 128 + 64 + lane], f2.y);
            atomicAdd(&acc[(u3 >> 17) * 128 + lane],      f3.x);
            atomicAdd(&acc[(u3 >> 17) * 128 + 64 + lane], f3.y);
        }
        for (; j < n; ++j) {
            uint u = __shfl(myv, j);
            float2 f = unpack2(h[(u & 0x1FFFFu) * 64 + lane]);
            atomicAdd(&acc[(u >> 17) * 128 + lane],      f.x);
            atomicAdd(&acc[(u >> 17) * 128 + 64 + lane], f.y);
        }
    }
    __syncthreads();
    const float s = 1.0f + epsv[layer];
    const int node0 = b * 128;
    for (int r = wave; r < 128; r += 8) {
        int g = node0 + r;
        if (g >= N_NODES) break;
        float2 own = unpack2(h[g * 64 + lane]);
        float x = s * own.x + acc[r * 128 + lane];
        float y = s * own.y + acc[r * 128 + 64 + lane];
        out[g * 64 + lane] = pack2(x, y);
    }
}

// ---------------- bf16 MFMA GEMM: C = act(A @ Wt^T + bias), in-place safe ----------------
#define GEMM_LDS_BYTES 69632
__global__ void __launch_bounds__(256) k_gemm(const ushort* __restrict__ A,
                                              const ushort* __restrict__ Wt,
                                              const float* __restrict__ bias,
                                              ushort* __restrict__ C,
                                              float* __restrict__ stats,
                                              int do_lrelu) {
    __shared__ char pool[GEMM_LDS_BYTES];
    ushort* As = (ushort*)pool;             // [128][136]
    ushort* Ws = (ushort*)(pool + 34816);   // [128][136]
    float*  Cs = (float*)pool;              // [128][132] (aliases As/Ws after sync)
    const int t = threadIdx.x;
    const int row0 = blockIdx.x * 128;
    {
        int r = t >> 1, hh = t & 1;
        uint4* l = (uint4*)(As + r * 136 + hh * 64);
        if (row0 + r < N_NODES) {
            const uint4* g = (const uint4*)(A + (size_t)(row0 + r) * DIM + hh * 64);
#pragma unroll
            for (int k = 0; k < 8; ++k) l[k] = g[k];
        } else {
            uint4 z = make_uint4(0, 0, 0, 0);
#pragma unroll
            for (int k = 0; k < 8; ++k) l[k] = z;
        }
        const uint4* gw = (const uint4*)(Wt + r * DIM + hh * 64);
        uint4* lw = (uint4*)(Ws + r * 136 + hh * 64);
#pragma unroll
        for (int k = 0; k < 8; ++k) lw[k] = gw[k];
    }
    __syncthreads();
    const int lane = t & 63, wave = t >> 6;
    const int q = lane >> 4, m = lane & 15;
    const int R = (wave >> 1) * 64, Cb = (wave & 1) * 64;
    f32x4 acc[4][4] = {};
#pragma unroll
    for (int ks = 0; ks < 4; ++ks) {
        bf16x8 a[4], b[4];
#pragma unroll
        for (int i = 0; i < 4; ++i)
            a[i] = *(const bf16x8*)(As + (R + i * 16 + m) * 136 + ks * 32 + q * 8);
#pragma unroll
        for (int j = 0; j < 4; ++j)
            b[j] = *(const bf16x8*)(Ws + (Cb + j * 16 + m) * 136 + ks * 32 + q * 8);
#pragma unroll
        for (int i = 0; i < 4; ++i)
#pragma unroll
            for (int j = 0; j < 4; ++j)
                acc[i][j] = __builtin_amdgcn_mfma_f32_16x16x32_bf16(a[i], b[j], acc[i][j], 0, 0, 0);
    }
    __syncthreads();
    float biasr[4];
#pragma unroll
    for (int j = 0; j < 4; ++j) biasr[j] = bias[Cb + j * 16 + m];
#pragma unroll
    for (int i = 0; i < 4; ++i)
#pragma unroll
        for (int j = 0; j < 4; ++j)
#pragma unroll
            for (int r = 0; r < 4; ++r)
                Cs[(R + i * 16 + q * 4 + r) * 132 + Cb + j * 16 + m] = acc[i][j][r] + biasr[j];
    __syncthreads();
    if (stats != nullptr && t < DIM) {
        int rows = N_NODES - row0; if (rows > 128) rows = 128;
        float s1 = 0.f, s2 = 0.f;
        for (int r = 0; r < rows; ++r) { float v = Cs[r * 132 + t]; s1 += v; s2 += v * v; }
        atomicAdd(&stats[t], s1);
        atomicAdd(&stats[DIM + t], s2);
    }
    {
        int r = t >> 1, hh = t & 1;
        if (row0 + r < N_NODES) {
            uint4* outp = (uint4*)(C + (size_t)(row0 + r) * DIM + hh * 64);
#pragma unroll
            for (int k = 0; k < 8; ++k) {
                float4 v0 = *(const float4*)(Cs + r * 132 + hh * 64 + k * 8);
                float4 v1 = *(const float4*)(Cs + r * 132 + hh * 64 + k * 8 + 4);
                if (do_lrelu) {
                    v0.x = lrelu(v0.x); v0.y = lrelu(v0.y); v0.z = lrelu(v0.z); v0.w = lrelu(v0.w);
                    v1.x = lrelu(v1.x); v1.y = lrelu(v1.y); v1.z = lrelu(v1.z); v1.w = lrelu(v1.w);
                }
                uint4 o;
                o.x = pack2(v0.x, v0.y); o.y = pack2(v0.z, v0.w);
                o.z = pack2(v1.x, v1.y); o.w = pack2(v1.z, v1.w);
                outp[k] = o;
            }
        }
    }
}

// ---------------- BN finalize: stats -> scale/shift ----------------
__global__ void k_bn_final(float* __restrict__ stats, const float* __restrict__ bn_g,
                           const float* __restrict__ bn_b, int layer) {
    int f = threadIdx.x;   // 128 threads
    float mean = stats[f] * (1.0f / N_NODES);
    float var  = stats[DIM + f] * (1.0f / N_NODES) - mean * mean;
    float inv  = rsqrtf(var + BN_EPS_F);
    float sc = bn_g[layer * DIM + f] * inv;
    float sh = bn_b[layer * DIM + f] - mean * sc;
    stats[f] = sc;
    stats[DIM + f] = sh;
}

// ---------------- BN apply + lrelu + fused pooling (bf16 in/out) ----------------
#define PROWS 128
__global__ void __launch_bounds__(256) k_bnpool(const uint* __restrict__ src,
                                                uint* __restrict__ dst,
                                                const float* __restrict__ stats,
                                                const int* __restrict__ batch,
                                                float* __restrict__ pooled, int colOff) {
    int c = threadIdx.x & 63;
    int chunk = threadIdx.x >> 6;
    int r0 = blockIdx.x * PROWS + chunk * (PROWS / 4);
    float sc0 = stats[2 * c], sc1 = stats[2 * c + 1];
    float sh0 = stats[DIM + 2 * c], sh1 = stats[DIM + 2 * c + 1];
    int curg = -1;
    float a0 = 0.f, a1 = 0.f;
    for (int i = 0; i < PROWS / 4; ++i) {
        int r = r0 + i;
        if (r >= N_NODES) break;
        float2 v = unpack2(src[r * 64 + c]);
        float x0 = lrelu(v.x * sc0 + sh0);
        float x1 = lrelu(v.y * sc1 + sh1);
        dst[r * 64 + c] = pack2(x0, x1);
        int g = batch[r];
        if (g != curg) {
            if (curg >= 0) {
                atomicAdd(&pooled[curg * CLS_IN + colOff + 2 * c], a0);
                atomicAdd(&pooled[curg * CLS_IN + colOff + 2 * c + 1], a1);
            }
            curg = g; a0 = 0.f; a1 = 0.f;
        }
        a0 += x0; a1 += x1;
    }
    if (curg >= 0) {
        atomicAdd(&pooled[curg * CLS_IN + colOff + 2 * c], a0);
        atomicAdd(&pooled[curg * CLS_IN + colOff + 2 * c + 1], a1);
    }
}

// ---------------- classifier head (fp32): one block per graph ----------------
__global__ void __launch_bounds__(256) k_classifier(const float* __restrict__ pooled,
                                                    const float* __restrict__ Wc1,
                                                    const float* __restrict__ bc1,
                                                    const float* __restrict__ Wc2,
                                                    const float* __restrict__ bc2,
                                                    float* __restrict__ out) {
    __shared__ float p[CLS_IN];
    __shared__ float hh[CLS_HID];
    int g = blockIdx.x, t = threadIdx.x;
    for (int j = t; j < CLS_IN; j += 256) p[j] = lrelu(pooled[g * CLS_IN + j]);
    __syncthreads();
    float acc = bc1[t];
    for (int k = 0; k < CLS_IN; ++k) acc += p[k] * Wc1[k * CLS_HID + t];
    hh[t] = lrelu(acc);
    __syncthreads();
    if (t < N_CLASSES) {
        float a2 = bc2[t];
        for (int k = 0; k < CLS_HID; ++k) a2 += hh[k] * Wc2[k * N_CLASSES + t];
        out[g * N_CLASSES + t] = a2;
    }
}

extern "C" void kernel_launch(void* const* d_in, const int* in_sizes, int n_in,
                              void* d_out, int out_size, void* d_ws, size_t ws_size,
                              hipStream_t stream) {
    const int*   deg   = (const int*)d_in[0];
    const int*   edges = (const int*)d_in[1];
    const int*   srcv  = edges;
    const int*   dstv  = edges + N_EDGES;
    const int*   batch = (const int*)d_in[2];
    const float* epsv  = (const float*)d_in[3];
    const float* W1    = (const float*)d_in[4];
    const float* b1    = (const float*)d_in[5];
    const float* W2    = (const float*)d_in[6];
    const float* b2    = (const float*)d_in[7];
    const float* bn_g  = (const float*)d_in[8];
    const float* bn_b  = (const float*)d_in[9];
    const float* Wc1   = (const float*)d_in[10];
    const float* bc1   = (const float*)d_in[11];
    const float* Wc2   = (const float*)d_in[12];
    const float* bc2   = (const float*)d_in[13];

    char* ws = (char*)d_ws;
    const size_t BUFB = (size_t)N_NODES * DIM * 2;   // 25,600,000 B (bf16)
    size_t off = 0;
    ushort* buf0   = (ushort*)(ws + off); off += BUFB;
    ushort* buf1   = (ushort*)(ws + off); off += BUFB;
    ushort* W1t    = (ushort*)(ws + off); off += 4 * DIM * DIM * 2;
    ushort* W2t    = (ushort*)(ws + off); off += 4 * DIM * DIM * 2;
    float*  pooled = (float*)(ws + off);  off += N_GRAPHS * CLS_IN * 4;
    float*  statsA = (float*)(ws + off);  off += 4 * 2 * DIM * 4;
    uint*   cursor = (uint*)(ws + off);   off += (NBUCK + 8) * 4;
    uint*   ebuf   = (uint*)(ws + off);   off += (size_t)NBUCK * BUCK_CAP * 4;  // 12.8 MB

    hipMemsetAsync(pooled, 0, N_GRAPHS * CLS_IN * 4, stream);
    hipMemsetAsync(statsA, 0, 4 * 2 * DIM * 4, stream);
    hipMemsetAsync(cursor, 0, NBUCK * 4, stream);

    k_convert_w<<<(8 * DIM * DIM + 255) / 256, 256, 0, stream>>>(W1, W2, W1t, W2t);
    k_build_x<<<(N_NODES * 64 + 255) / 256, 256, 0, stream>>>(deg, (uint*)buf0);
    k_deg_pool<<<(N_NODES + 255) / 256, 256, 0, stream>>>(deg, batch, pooled);
    k_partition<<<(N_EDGES + 16383) / 16384, 1024, 0, stream>>>(srcv, dstv, cursor, ebuf);

    const int gemm_grid = (N_NODES + 127) / 128;   // 782
    for (int l = 0; l < N_LAYERS; ++l) {
        float* stats = statsA + l * 2 * DIM;
        k_agg<<<NBUCK, 512, 0, stream>>>((const uint*)buf0, ebuf, cursor,
                                         (uint*)buf1, epsv, l);
        k_gemm<<<gemm_grid, 256, 0, stream>>>(buf1, W1t + l * DIM * DIM, b1 + l * DIM,
                                              buf1, nullptr, 1);
        k_gemm<<<gemm_grid, 256, 0, stream>>>(buf1, W2t + l * DIM * DIM, b2 + l * DIM,
                                              buf1, stats, 0);
        k_bn_final<<<1, DIM, 0, stream>>>(stats, bn_g, bn_b, l);
        k_bnpool<<<(N_NODES + PROWS - 1) / PROWS, 256, 0, stream>>>(
            (const uint*)buf1, (uint*)buf0, stats, batch, pooled, DIM * (l + 1));
    }

    k_classifier<<<N_GRAPHS, 256, 0, stream>>>(pooled, Wc1, bc1, Wc2, bc2, (float*)d_out);
}

// Round 4
// 721.543 us; speedup vs baseline: 8.1275x; 8.1275x over previous
//
#include <hip/hip_runtime.h>
#include <hip/hip_bf16.h>

// GIN: N=100000, E=1.6M, G=64, D=128, L=4.
// R4: bucketed edge partition (kept from R3) + per-bucket in-LDS counting sort
// + REGISTER-accumulating gather (R2's proven inner loop; no LDS float atomics).
// bf16 feature storage, bf16 MFMA GEMMs with fused BN stats, fused bnpool.

#define N_NODES   100000
#define N_EDGES   1600000
#define N_GRAPHS  64
#define DIM       128
#define N_LAYERS  4
#define CLS_IN    640
#define CLS_HID   256
#define N_CLASSES 10
#define LRELU_SLOPE 0.01f
#define BN_EPS_F    1e-5f

#define NBUCK    782      // ceil(100000/128)
#define BUCK_CAP 4096     // avg fill 2046 -> plenty of headroom

typedef __attribute__((ext_vector_type(8))) short bf16x8;
typedef __attribute__((ext_vector_type(4))) float f32x4;

__device__ __forceinline__ float lrelu(float x) { return x > 0.f ? x : LRELU_SLOPE * x; }

__device__ __forceinline__ uint pack2(float x, float y) {
    uint a = __float_as_uint(x), b = __float_as_uint(y);
    a = (a + 0x7FFFu + ((a >> 16) & 1u)) >> 16;
    b = (b + 0x7FFFu + ((b >> 16) & 1u)) >> 16;
    return a | (b << 16);
}
__device__ __forceinline__ float2 unpack2(uint v) {
    return make_float2(__uint_as_float(v << 16), __uint_as_float(v & 0xFFFF0000u));
}

// ---------------- weight convert: W[k][n] fp32 -> Wt[n][k] bf16 ----------------
__global__ void k_convert_w(const float* __restrict__ W1, const float* __restrict__ W2,
                            ushort* __restrict__ W1t, ushort* __restrict__ W2t) {
    int gid = blockIdx.x * blockDim.x + threadIdx.x;   // 8 * 16384
    if (gid >= 8 * DIM * DIM) return;
    int mat = gid >> 14, idx = gid & 16383;
    int k = idx >> 7, n = idx & 127;
    const float* src = (mat < 4) ? (W1 + mat * DIM * DIM) : (W2 + (mat - 4) * DIM * DIM);
    ushort* dst = (mat < 4) ? (W1t + mat * DIM * DIM) : (W2t + (mat - 4) * DIM * DIM);
    uint a = __float_as_uint(src[k * DIM + n]);
    dst[n * DIM + k] = (ushort)((a + 0x7FFFu + ((a >> 16) & 1u)) >> 16);
}

// ---------------- initial one-hot features (bf16) ----------------
__global__ void k_build_x(const int* __restrict__ deg, uint* __restrict__ x) {
    int gid = blockIdx.x * blockDim.x + threadIdx.x;   // one per uint (2 bf16)
    if (gid >= N_NODES * 64) return;
    int i = gid >> 6, c = gid & 63;
    int d = deg[i];
    uint v = 0;
    if ((d >> 1) == c) v = 0x3F80u << (16 * (d & 1));
    x[gid] = v;
}

// zs[0] pooling = per-graph degree histogram
__global__ void k_deg_pool(const int* __restrict__ deg, const int* __restrict__ batch,
                           float* __restrict__ pooled) {
    int i = blockIdx.x * blockDim.x + threadIdx.x;
    if (i < N_NODES) atomicAdd(&pooled[batch[i] * CLS_IN + deg[i]], 1.0f);
}

// ---------------- single-pass bucketed edge partition ----------------
// bucket b = dst >> 7 covers nodes [128b, 128b+128); packed = (dst&127)<<17 | src
__global__ void __launch_bounds__(1024) k_partition(const int* __restrict__ src,
                                                    const int* __restrict__ dst,
                                                    uint* __restrict__ cursor,
                                                    uint* __restrict__ ebuf) {
    __shared__ uint hist[NBUCK];
    __shared__ uint basev[NBUCK];
    int t = threadIdx.x;
    for (int b = t; b < NBUCK; b += 1024) hist[b] = 0;
    __syncthreads();
    int e0 = blockIdx.x * 16384;
    uint msrc[16], mdst[16], mrank[16];
#pragma unroll
    for (int i = 0; i < 16; ++i) {
        int e = e0 + i * 1024 + t;
        if (e < N_EDGES) {
            msrc[i] = (uint)src[e];
            mdst[i] = (uint)dst[e];
            mrank[i] = atomicAdd(&hist[mdst[i] >> 7], 1u);
        } else mdst[i] = 0xFFFFFFFFu;
    }
    __syncthreads();
    for (int b = t; b < NBUCK; b += 1024) {
        uint c = hist[b];
        basev[b] = c ? (uint)(b * BUCK_CAP) + atomicAdd(&cursor[b], c) : 0u;
    }
    __syncthreads();
#pragma unroll
    for (int i = 0; i < 16; ++i) {
        if (mdst[i] != 0xFFFFFFFFu) {
            uint b = mdst[i] >> 7;
            ebuf[basev[b] + mrank[i]] = ((mdst[i] & 127u) << 17) | msrc[i];
        }
    }
}

// ---------------- aggregation: in-LDS counting sort + register gather ----------------
// out[n] = (1+eps)*h[n] + sum_{e: dst=n} h[src_e]
__global__ void __launch_bounds__(512) k_agg(const uint* __restrict__ h,
                                             const uint* __restrict__ ebuf,
                                             const uint* __restrict__ cursor,
                                             uint* __restrict__ out,
                                             const float* __restrict__ epsv, int layer) {
    __shared__ uint sortedL[BUCK_CAP];   // 16 KB
    __shared__ uint hist[128];
    __shared__ uint startv[129];
    const int t = threadIdx.x, lane = t & 63, wave = t >> 6;
    const int b = blockIdx.x;
    int cnt = (int)cursor[b]; if (cnt > BUCK_CAP) cnt = BUCK_CAP;
    if (t < 128) hist[t] = 0;
    __syncthreads();
    // pass 1: load edges to registers, rank via LDS int histogram
    uint ent[8], rank[8];
    const uint* ep = ebuf + b * BUCK_CAP;
#pragma unroll
    for (int k = 0; k < 8; ++k) {
        int i = t + k * 512;
        if (i < cnt) { ent[k] = ep[i]; rank[k] = atomicAdd(&hist[ent[k] >> 17], 1u); }
    }
    __syncthreads();
    // exclusive scan: startv[r+1] = sum hist[0..r]
    if (t < 128) startv[t + 1] = hist[t];
    if (t == 0) startv[0] = 0;
    __syncthreads();
    for (int off = 1; off < 128; off <<= 1) {
        uint add = (t < 128 && t >= off) ? startv[t + 1 - off] : 0u;
        __syncthreads();
        if (t < 128 && t >= off) startv[t + 1] += add;
        __syncthreads();
    }
    // scatter into dst-sorted LDS edge array
#pragma unroll
    for (int k = 0; k < 8; ++k) {
        int i = t + k * 512;
        if (i < cnt) sortedL[startv[ent[k] >> 17] + rank[k]] = ent[k];
    }
    __syncthreads();
    // pass 2: register-accumulating gather, wave owns 16 consecutive nodes
    const float s = 1.0f + epsv[layer];
    const int node0 = b * 128;
    for (int ri = 0; ri < 16; ++ri) {
        int r = wave * 16 + ri;
        int g = node0 + r;
        if (g >= N_NODES) break;
        int beg = (int)startv[r], end = (int)startv[r + 1];
        float2 own = unpack2(h[g * 64 + lane]);
        float ax = s * own.x, ay = s * own.y;
        int j = beg;
        for (; j + 4 <= end; j += 4) {
            uint u0 = sortedL[j]     & 0x1FFFFu;
            uint u1 = sortedL[j + 1] & 0x1FFFFu;
            uint u2 = sortedL[j + 2] & 0x1FFFFu;
            uint u3 = sortedL[j + 3] & 0x1FFFFu;
            uint h0 = h[u0 * 64 + lane], h1 = h[u1 * 64 + lane];
            uint h2 = h[u2 * 64 + lane], h3 = h[u3 * 64 + lane];
            float2 f0 = unpack2(h0), f1 = unpack2(h1), f2 = unpack2(h2), f3 = unpack2(h3);
            ax += (f0.x + f1.x) + (f2.x + f3.x);
            ay += (f0.y + f1.y) + (f2.y + f3.y);
        }
        for (; j < end; ++j) {
            uint u = sortedL[j] & 0x1FFFFu;
            float2 f = unpack2(h[u * 64 + lane]);
            ax += f.x; ay += f.y;
        }
        out[g * 64 + lane] = pack2(ax, ay);
    }
}

// ---------------- bf16 MFMA GEMM: C = act(A @ Wt^T + bias), in-place safe ----------------
#define GEMM_LDS_BYTES 69632
__global__ void __launch_bounds__(256) k_gemm(const ushort* __restrict__ A,
                                              const ushort* __restrict__ Wt,
                                              const float* __restrict__ bias,
                                              ushort* __restrict__ C,
                                              float* __restrict__ stats,
                                              int do_lrelu) {
    __shared__ char pool[GEMM_LDS_BYTES];
    ushort* As = (ushort*)pool;             // [128][136]
    ushort* Ws = (ushort*)(pool + 34816);   // [128][136]
    float*  Cs = (float*)pool;              // [128][132] (aliases As/Ws after sync)
    const int t = threadIdx.x;
    const int row0 = blockIdx.x * 128;
    {
        int r = t >> 1, hh = t & 1;
        uint4* l = (uint4*)(As + r * 136 + hh * 64);
        if (row0 + r < N_NODES) {
            const uint4* g = (const uint4*)(A + (size_t)(row0 + r) * DIM + hh * 64);
#pragma unroll
            for (int k = 0; k < 8; ++k) l[k] = g[k];
        } else {
            uint4 z = make_uint4(0, 0, 0, 0);
#pragma unroll
            for (int k = 0; k < 8; ++k) l[k] = z;
        }
        const uint4* gw = (const uint4*)(Wt + r * DIM + hh * 64);
        uint4* lw = (uint4*)(Ws + r * 136 + hh * 64);
#pragma unroll
        for (int k = 0; k < 8; ++k) lw[k] = gw[k];
    }
    __syncthreads();
    const int lane = t & 63, wave = t >> 6;
    const int q = lane >> 4, m = lane & 15;
    const int R = (wave >> 1) * 64, Cb = (wave & 1) * 64;
    f32x4 acc[4][4] = {};
#pragma unroll
    for (int ks = 0; ks < 4; ++ks) {
        bf16x8 a[4], b[4];
#pragma unroll
        for (int i = 0; i < 4; ++i)
            a[i] = *(const bf16x8*)(As + (R + i * 16 + m) * 136 + ks * 32 + q * 8);
#pragma unroll
        for (int j = 0; j < 4; ++j)
            b[j] = *(const bf16x8*)(Ws + (Cb + j * 16 + m) * 136 + ks * 32 + q * 8);
#pragma unroll
        for (int i = 0; i < 4; ++i)
#pragma unroll
            for (int j = 0; j < 4; ++j)
                acc[i][j] = __builtin_amdgcn_mfma_f32_16x16x32_bf16(a[i], b[j], acc[i][j], 0, 0, 0);
    }
    __syncthreads();
    float biasr[4];
#pragma unroll
    for (int j = 0; j < 4; ++j) biasr[j] = bias[Cb + j * 16 + m];
#pragma unroll
    for (int i = 0; i < 4; ++i)
#pragma unroll
        for (int j = 0; j < 4; ++j)
#pragma unroll
            for (int r = 0; r < 4; ++r)
                Cs[(R + i * 16 + q * 4 + r) * 132 + Cb + j * 16 + m] = acc[i][j][r] + biasr[j];
    __syncthreads();
    if (stats != nullptr && t < DIM) {
        int rows = N_NODES - row0; if (rows > 128) rows = 128;
        float s1 = 0.f, s2 = 0.f;
        for (int r = 0; r < rows; ++r) { float v = Cs[r * 132 + t]; s1 += v; s2 += v * v; }
        atomicAdd(&stats[t], s1);
        atomicAdd(&stats[DIM + t], s2);
    }
    {
        int r = t >> 1, hh = t & 1;
        if (row0 + r < N_NODES) {
            uint4* outp = (uint4*)(C + (size_t)(row0 + r) * DIM + hh * 64);
#pragma unroll
            for (int k = 0; k < 8; ++k) {
                float4 v0 = *(const float4*)(Cs + r * 132 + hh * 64 + k * 8);
                float4 v1 = *(const float4*)(Cs + r * 132 + hh * 64 + k * 8 + 4);
                if (do_lrelu) {
                    v0.x = lrelu(v0.x); v0.y = lrelu(v0.y); v0.z = lrelu(v0.z); v0.w = lrelu(v0.w);
                    v1.x = lrelu(v1.x); v1.y = lrelu(v1.y); v1.z = lrelu(v1.z); v1.w = lrelu(v1.w);
                }
                uint4 o;
                o.x = pack2(v0.x, v0.y); o.y = pack2(v0.z, v0.w);
                o.z = pack2(v1.x, v1.y); o.w = pack2(v1.z, v1.w);
                outp[k] = o;
            }
        }
    }
}

// ---------------- BN finalize: stats -> scale/shift ----------------
__global__ void k_bn_final(float* __restrict__ stats, const float* __restrict__ bn_g,
                           const float* __restrict__ bn_b, int layer) {
    int f = threadIdx.x;   // 128 threads
    float mean = stats[f] * (1.0f / N_NODES);
    float var  = stats[DIM + f] * (1.0f / N_NODES) - mean * mean;
    float inv  = rsqrtf(var + BN_EPS_F);
    float sc = bn_g[layer * DIM + f] * inv;
    float sh = bn_b[layer * DIM + f] - mean * sc;
    stats[f] = sc;
    stats[DIM + f] = sh;
}

// ---------------- BN apply + lrelu + fused pooling (bf16 in/out) ----------------
#define PROWS 128
__global__ void __launch_bounds__(256) k_bnpool(const uint* __restrict__ src,
                                                uint* __restrict__ dst,
                                                const float* __restrict__ stats,
                                                const int* __restrict__ batch,
                                                float* __restrict__ pooled, int colOff) {
    int c = threadIdx.x & 63;
    int chunk = threadIdx.x >> 6;
    int r0 = blockIdx.x * PROWS + chunk * (PROWS / 4);
    float sc0 = stats[2 * c], sc1 = stats[2 * c + 1];
    float sh0 = stats[DIM + 2 * c], sh1 = stats[DIM + 2 * c + 1];
    int curg = -1;
    float a0 = 0.f, a1 = 0.f;
    for (int i = 0; i < PROWS / 4; ++i) {
        int r = r0 + i;
        if (r >= N_NODES) break;
        float2 v = unpack2(src[r * 64 + c]);
        float x0 = lrelu(v.x * sc0 + sh0);
        float x1 = lrelu(v.y * sc1 + sh1);
        dst[r * 64 + c] = pack2(x0, x1);
        int g = batch[r];
        if (g != curg) {
            if (curg >= 0) {
                atomicAdd(&pooled[curg * CLS_IN + colOff + 2 * c], a0);
                atomicAdd(&pooled[curg * CLS_IN + colOff + 2 * c + 1], a1);
            }
            curg = g; a0 = 0.f; a1 = 0.f;
        }
        a0 += x0; a1 += x1;
    }
    if (curg >= 0) {
        atomicAdd(&pooled[curg * CLS_IN + colOff + 2 * c], a0);
        atomicAdd(&pooled[curg * CLS_IN + colOff + 2 * c + 1], a1);
    }
}

// ---------------- classifier head (fp32): one block per graph ----------------
__global__ void __launch_bounds__(256) k_classifier(const float* __restrict__ pooled,
                                                    const float* __restrict__ Wc1,
                                                    const float* __restrict__ bc1,
                                                    const float* __restrict__ Wc2,
                                                    const float* __restrict__ bc2,
                                                    float* __restrict__ out) {
    __shared__ float p[CLS_IN];
    __shared__ float hh[CLS_HID];
    int g = blockIdx.x, t = threadIdx.x;
    for (int j = t; j < CLS_IN; j += 256) p[j] = lrelu(pooled[g * CLS_IN + j]);
    __syncthreads();
    float acc = bc1[t];
    for (int k = 0; k < CLS_IN; ++k) acc += p[k] * Wc1[k * CLS_HID + t];
    hh[t] = lrelu(acc);
    __syncthreads();
    if (t < N_CLASSES) {
        float a2 = bc2[t];
        for (int k = 0; k < CLS_HID; ++k) a2 += hh[k] * Wc2[k * N_CLASSES + t];
        out[g * N_CLASSES + t] = a2;
    }
}

extern "C" void kernel_launch(void* const* d_in, const int* in_sizes, int n_in,
                              void* d_out, int out_size, void* d_ws, size_t ws_size,
                              hipStream_t stream) {
    const int*   deg   = (const int*)d_in[0];
    const int*   edges = (const int*)d_in[1];
    const int*   srcv  = edges;
    const int*   dstv  = edges + N_EDGES;
    const int*   batch = (const int*)d_in[2];
    const float* epsv  = (const float*)d_in[3];
    const float* W1    = (const float*)d_in[4];
    const float* b1    = (const float*)d_in[5];
    const float* W2    = (const float*)d_in[6];
    const float* b2    = (const float*)d_in[7];
    const float* bn_g  = (const float*)d_in[8];
    const float* bn_b  = (const float*)d_in[9];
    const float* Wc1   = (const float*)d_in[10];
    const float* bc1   = (const float*)d_in[11];
    const float* Wc2   = (const float*)d_in[12];
    const float* bc2   = (const float*)d_in[13];

    char* ws = (char*)d_ws;
    const size_t BUFB = (size_t)N_NODES * DIM * 2;   // 25,600,000 B (bf16)
    size_t off = 0;
    ushort* buf0   = (ushort*)(ws + off); off += BUFB;
    ushort* buf1   = (ushort*)(ws + off); off += BUFB;
    ushort* W1t    = (ushort*)(ws + off); off += 4 * DIM * DIM * 2;
    ushort* W2t    = (ushort*)(ws + off); off += 4 * DIM * DIM * 2;
    float*  pooled = (float*)(ws + off);  off += N_GRAPHS * CLS_IN * 4;
    float*  statsA = (float*)(ws + off);  off += 4 * 2 * DIM * 4;
    uint*   cursor = (uint*)(ws + off);   off += (NBUCK + 8) * 4;
    uint*   ebuf   = (uint*)(ws + off);   off += (size_t)NBUCK * BUCK_CAP * 4;  // 12.8 MB

    hipMemsetAsync(pooled, 0, N_GRAPHS * CLS_IN * 4, stream);
    hipMemsetAsync(statsA, 0, 4 * 2 * DIM * 4, stream);
    hipMemsetAsync(cursor, 0, NBUCK * 4, stream);

    k_convert_w<<<(8 * DIM * DIM + 255) / 256, 256, 0, stream>>>(W1, W2, W1t, W2t);
    k_build_x<<<(N_NODES * 64 + 255) / 256, 256, 0, stream>>>(deg, (uint*)buf0);
    k_deg_pool<<<(N_NODES + 255) / 256, 256, 0, stream>>>(deg, batch, pooled);
    k_partition<<<(N_EDGES + 16383) / 16384, 1024, 0, stream>>>(srcv, dstv, cursor, ebuf);

    const int gemm_grid = (N_NODES + 127) / 128;   // 782
    for (int l = 0; l < N_LAYERS; ++l) {
        float* stats = statsA + l * 2 * DIM;
        k_agg<<<NBUCK, 512, 0, stream>>>((const uint*)buf0, ebuf, cursor,
                                         (uint*)buf1, epsv, l);
        k_gemm<<<gemm_grid, 256, 0, stream>>>(buf1, W1t + l * DIM * DIM, b1 + l * DIM,
                                              buf1, nullptr, 1);
        k_gemm<<<gemm_grid, 256, 0, stream>>>(buf1, W2t + l * DIM * DIM, b2 + l * DIM,
                                              buf1, stats, 0);
        k_bn_final<<<1, DIM, 0, stream>>>(stats, bn_g, bn_b, l);
        k_bnpool<<<(N_NODES + PROWS - 1) / PROWS, 256, 0, stream>>>(
            (const uint*)buf1, (uint*)buf0, stats, batch, pooled, DIM * (l + 1));
    }

    k_classifier<<<N_GRAPHS, 256, 0, stream>>>(pooled, Wc1, bc1, Wc2, bc2, (float*)d_out);
}